// Round 1
// 1636.992 us; speedup vs baseline: 3.2456x; 3.2456x over previous
//
#include <hip/hip_runtime.h>
#include <math.h>

// Problem constants (B=1 throughout)
constexpr int SQ = 2048, SK = 3072, TT = 4096, DM = 2048;
constexpr int H = 16, HKV = 8, D = 128, FF = 6144;
#define EPS 1e-6f

typedef __attribute__((ext_vector_type(8))) short short8;   // 8 bf16 = 4 VGPRs
typedef __attribute__((ext_vector_type(4))) float f32x4;    // MFMA accum

#define GLOBAL_AS __attribute__((address_space(1)))
#define LDS_AS __attribute__((address_space(3)))

__device__ __forceinline__ unsigned short f2bf(float f) {
  unsigned u = __float_as_uint(f);
  unsigned r = (u + 0x7fffu + ((u >> 16) & 1u)) >> 16;
  return (unsigned short)r;
}
__device__ __forceinline__ float bflo(unsigned w) { return __uint_as_float(w << 16); }
__device__ __forceinline__ float bfhi(unsigned w) { return __uint_as_float(w & 0xffff0000u); }

// ---------------------------------------------------------------------------
// Weight transpose + f32->bf16 cast: w[K][N] f32  ->  wT[N][K] bf16.
// grid = (N/64, K/64), block 256. LDS pad 73 (odd) keeps both phases ~2-way.
// ---------------------------------------------------------------------------
__global__ __launch_bounds__(256) void wt_bf16_kernel(
    const float* __restrict__ w, unsigned short* __restrict__ wT, int K, int N) {
  __shared__ unsigned short s[64][73];
  int n0 = blockIdx.x * 64, k0 = blockIdx.y * 64;
  int tid = threadIdx.x;
  int cn = (tid & 15) * 4, rk = tid >> 4;
#pragma unroll
  for (int p = 0; p < 4; p++) {
    int k = rk + p * 16;
    const float4 f = *(const float4*)&w[(size_t)(k0 + k) * N + n0 + cn];
    s[k][cn] = f2bf(f.x); s[k][cn + 1] = f2bf(f.y);
    s[k][cn + 2] = f2bf(f.z); s[k][cn + 3] = f2bf(f.w);
  }
  __syncthreads();
  int ck = (tid & 15) * 4, rn = tid >> 4;
#pragma unroll
  for (int p = 0; p < 4; p++) {
    int n = rn + p * 16;
    ushort4 o;
    o.x = s[ck][n]; o.y = s[ck + 1][n]; o.z = s[ck + 2][n]; o.w = s[ck + 3][n];
    *(ushort4*)&wT[(size_t)(n0 + n) * K + k0 + ck] = o;
  }
}

// ---------------------------------------------------------------------------
// RMSNorm over DM=2048 cols, f32 in -> bf16 out. block 256 (8 elems/thread).
// ---------------------------------------------------------------------------
__global__ __launch_bounds__(256) void rmsnorm_bf16_kernel(
    const float* __restrict__ x, const float* __restrict__ w,
    unsigned short* __restrict__ y) {
  int row = blockIdx.x;
  const float* xr = x + (size_t)row * DM;
  int c = threadIdx.x * 8;
  float4 a = *(const float4*)&xr[c];
  float4 b = *(const float4*)&xr[c + 4];
  float ss = a.x * a.x + a.y * a.y + a.z * a.z + a.w * a.w +
             b.x * b.x + b.y * b.y + b.z * b.z + b.w * b.w;
  for (int o = 32; o > 0; o >>= 1) ss += __shfl_down(ss, o);
  __shared__ float sred[4];
  int lane = threadIdx.x & 63, wid = threadIdx.x >> 6;
  if (lane == 0) sred[wid] = ss;
  __syncthreads();
  if (threadIdx.x == 0)
    sred[0] = rsqrtf((sred[0] + sred[1] + sred[2] + sred[3]) * (1.0f / (float)DM) + EPS);
  __syncthreads();
  float sc = sred[0];
  float4 wa = *(const float4*)&w[c];
  float4 wb = *(const float4*)&w[c + 4];
  ushort4 o1, o2;
  o1.x = f2bf(a.x * sc * wa.x); o1.y = f2bf(a.y * sc * wa.y);
  o1.z = f2bf(a.z * sc * wa.z); o1.w = f2bf(a.w * sc * wa.w);
  o2.x = f2bf(b.x * sc * wb.x); o2.y = f2bf(b.y * sc * wb.y);
  o2.z = f2bf(b.z * sc * wb.z); o2.w = f2bf(b.w * sc * wb.w);
  unsigned short* yr = y + (size_t)row * DM + c;
  *(ushort4*)&yr[0] = o1;
  *(ushort4*)&yr[4] = o2;
}

// ---------------------------------------------------------------------------
// bf16 MFMA GEMM (m97 structure): C[M,N] = A[M,K] @ BT[N,K]^T (+ Add)
// 128x128 tile, BK=64, 4 waves x (64x64), mfma_f32_16x16x32_bf16.
// Staging: global_load_lds width 16, linear LDS dest, XOR-swizzled SOURCE
// chunk (rule #21); fragment ds_read_b128 applies the same XOR -> ~2-way.
// ---------------------------------------------------------------------------
template <bool ADD, bool OUTBF>
__global__ __launch_bounds__(256) void mgemm_kernel(
    const unsigned short* __restrict__ A, const unsigned short* __restrict__ BT,
    const float* __restrict__ Add, void* __restrict__ Cp,
    int M, int N, int K) {
  __shared__ unsigned short As[128 * 64];
  __shared__ unsigned short Bs[128 * 64];
  const int tid = threadIdx.x;
  const int wave = tid >> 6, lane = tid & 63;
  const int bm = blockIdx.y * 128, bn = blockIdx.x * 128;
  const int wr = wave >> 1, wc = wave & 1;  // wave owns 64x64 at (wr,wc)
  const int fl = lane & 15, fk = lane >> 4; // fragment row/col, k-group

  // staging geometry: per pass, each wave fills 8 rows (64 lanes x 16B = 1KB)
  const int srow = wave * 8 + (lane >> 3);         // row within 32-row pass
  const int schunk = (lane & 7) ^ (srow & 7);      // pre-swizzled src chunk
  const unsigned short* Abase = A + (size_t)(bm + srow) * K + schunk * 8;
  const unsigned short* Bbase = BT + (size_t)(bn + srow) * K + schunk * 8;

  f32x4 acc[4][4];
#pragma unroll
  for (int m = 0; m < 4; m++)
#pragma unroll
    for (int n = 0; n < 4; n++)
#pragma unroll
      for (int e = 0; e < 4; e++) acc[m][n][e] = 0.f;

  for (int k0 = 0; k0 < K; k0 += 64) {
#pragma unroll
    for (int p = 0; p < 4; p++) {
      __builtin_amdgcn_global_load_lds(
          (GLOBAL_AS unsigned*)(Abase + (size_t)(p * 32) * K + k0),
          (LDS_AS unsigned*)&As[(p * 32 + wave * 8) * 64], 16, 0, 0);
      __builtin_amdgcn_global_load_lds(
          (GLOBAL_AS unsigned*)(Bbase + (size_t)(p * 32) * K + k0),
          (LDS_AS unsigned*)&Bs[(p * 32 + wave * 8) * 64], 16, 0, 0);
    }
    __syncthreads();  // vmcnt(0) drain: tiles resident
#pragma unroll
    for (int kk = 0; kk < 2; kk++) {
      short8 a_[4], b_[4];
#pragma unroll
      for (int m = 0; m < 4; m++) {
        int row = wr * 64 + m * 16 + fl;
        int ch = (kk * 4 + fk) ^ (row & 7);
        a_[m] = *(const short8*)&As[row * 64 + ch * 8];
      }
#pragma unroll
      for (int n = 0; n < 4; n++) {
        int row = wc * 64 + n * 16 + fl;
        int ch = (kk * 4 + fk) ^ (row & 7);
        b_[n] = *(const short8*)&Bs[row * 64 + ch * 8];
      }
#pragma unroll
      for (int m = 0; m < 4; m++)
#pragma unroll
        for (int n = 0; n < 4; n++)
          acc[m][n] = __builtin_amdgcn_mfma_f32_16x16x32_bf16(
              a_[m], b_[n], acc[m][n], 0, 0, 0);
    }
    __syncthreads();  // compute done before next-tile overwrite
  }

  // epilogue: C/D layout col=lane&15, row=4*(lane>>4)+r (guide §3, verified)
#pragma unroll
  for (int m = 0; m < 4; m++) {
    int row0 = bm + wr * 64 + m * 16 + fk * 4;
#pragma unroll
    for (int n = 0; n < 4; n++) {
      int col = bn + wc * 64 + n * 16 + fl;
#pragma unroll
      for (int r = 0; r < 4; r++) {
        size_t idx = (size_t)(row0 + r) * N + col;
        float v = acc[m][n][r];
        if (ADD) v += Add[idx];
        if (OUTBF) ((unsigned short*)Cp)[idx] = f2bf(v);
        else ((float*)Cp)[idx] = v;
      }
    }
  }
}

// ---------------------------------------------------------------------------
// Per-head RMSNorm (over D=128) + RoPE, in place (f32).
// ---------------------------------------------------------------------------
__global__ __launch_bounds__(128) void qknorm_rope_kernel(
    float* __restrict__ x, const float* __restrict__ nw,
    const int* __restrict__ pos, int nheads) {
  int s = blockIdx.x, hh = blockIdx.y;
  float* xr = x + ((size_t)s * nheads + hh) * D;
  int d = threadIdx.x;
  float vv = xr[d];
  float ss = vv * vv;
  for (int o = 32; o > 0; o >>= 1) ss += __shfl_down(ss, o);
  __shared__ float sred[2];
  __shared__ float sn[D];
  if ((d & 63) == 0) sred[d >> 6] = ss;
  __syncthreads();
  float ms = (sred[0] + sred[1]) * (1.0f / (float)D);
  float n = vv * rsqrtf(ms + EPS) * nw[d];
  sn[d] = n;
  __syncthreads();
  int t = d & 63;
  float inv = powf(1000000.0f, -((float)(2 * t)) / (float)D);
  float ang = (float)pos[s] * inv;
  float c = cosf(ang), si = sinf(ang);
  float rh = (d < 64) ? -sn[d + 64] : sn[d - 64];
  xr[d] = n * c + rh * si;
}

// ---------------------------------------------------------------------------
// Pre-gather mask: maskg[q][j] = mask[hs_idxs[q]*TT + key_idxs[j]]
// ---------------------------------------------------------------------------
__global__ __launch_bounds__(256) void mask_gather_kernel(
    const float* __restrict__ mask, const int* __restrict__ hs_idxs,
    const int* __restrict__ key_idxs, float* __restrict__ maskg) {
  int q = blockIdx.x;
  const float* base = mask + (size_t)hs_idxs[q] * TT;
  float* out = maskg + (size_t)q * SK;
  for (int j = threadIdx.x; j < SK; j += 256) out[j] = base[key_idxs[j]];
}

// ---------------------------------------------------------------------------
// Tiled flash attention, bf16-in-LDS, f32 accum. grid = (SQ/64, H), block 256.
// q: [SQ][H][D], k/v: [SK][HKV][D] (f32), maskg: [SQ][SK], ctx: bf16 [SQ][H*D]
// ---------------------------------------------------------------------------
__global__ __launch_bounds__(256) void attn_kernel(
    const float* __restrict__ q, const float* __restrict__ k,
    const float* __restrict__ v, const float* __restrict__ maskg,
    unsigned short* __restrict__ ctx) {
  __shared__ unsigned QsU[64 * 65];
  __shared__ unsigned KsU[64 * 65];   // reused as f32 Sg[64][65] in PV phase
  __shared__ unsigned VsU[64 * 65];
  float* Sg = (float*)KsU;

  const int tid = threadIdx.x;
  const int tx = tid & 15, ty = tid >> 4;
  const int qblk = blockIdx.x * 64;
  const int hh = blockIdx.y;
  const int kvh = hh >> 1;  // H/HKV == 2
  const float scale = 0.08838834764831845f;  // 128^-0.5

  const int srow = tid >> 5;
  const int d4 = tid & 31;

#pragma unroll
  for (int i = 0; i < 8; i++) {
    int r = i * 8 + srow;
    const float4 f = *(const float4*)&q[(((size_t)(qblk + r)) * H + hh) * D + 4 * d4];
    QsU[r * 65 + 2 * d4]     = ((unsigned)f2bf(f.y) << 16) | f2bf(f.x);
    QsU[r * 65 + 2 * d4 + 1] = ((unsigned)f2bf(f.w) << 16) | f2bf(f.z);
  }

  float m_i[4], l_i[4], o[4][8];
#pragma unroll
  for (int i = 0; i < 4; i++) {
    m_i[i] = -INFINITY; l_i[i] = 0.f;
#pragma unroll
    for (int c = 0; c < 8; c++) o[i][c] = 0.f;
  }

  for (int j0 = 0; j0 < SK; j0 += 64) {
    __syncthreads();
#pragma unroll
    for (int i = 0; i < 8; i++) {
      int r = i * 8 + srow;
      size_t gbase = (((size_t)(j0 + r)) * HKV + kvh) * D + 4 * d4;
      const float4 fk = *(const float4*)&k[gbase];
      KsU[r * 65 + 2 * d4]     = ((unsigned)f2bf(fk.y) << 16) | f2bf(fk.x);
      KsU[r * 65 + 2 * d4 + 1] = ((unsigned)f2bf(fk.w) << 16) | f2bf(fk.z);
      const float4 fv = *(const float4*)&v[gbase];
      VsU[r * 65 + 2 * d4]     = ((unsigned)f2bf(fv.y) << 16) | f2bf(fv.x);
      VsU[r * 65 + 2 * d4 + 1] = ((unsigned)f2bf(fv.w) << 16) | f2bf(fv.z);
    }
    float mk[4][4];
#pragma unroll
    for (int i = 0; i < 4; i++)
#pragma unroll
      for (int j = 0; j < 4; j++)
        mk[i][j] = maskg[(size_t)(qblk + 4 * ty + i) * SK + j0 + 4 * tx + j];
    __syncthreads();

    float s[4][4] = {};
#pragma unroll 4
    for (int dp = 0; dp < 64; dp++) {
      unsigned qw[4], kw[4];
#pragma unroll
      for (int i = 0; i < 4; i++) qw[i] = QsU[(4 * ty + i) * 65 + dp];
#pragma unroll
      for (int j = 0; j < 4; j++) kw[j] = KsU[(4 * tx + j) * 65 + dp];
#pragma unroll
      for (int i = 0; i < 4; i++) {
        float ql = bflo(qw[i]), qh = bfhi(qw[i]);
#pragma unroll
        for (int j = 0; j < 4; j++) {
          s[i][j] += ql * bflo(kw[j]);
          s[i][j] += qh * bfhi(kw[j]);
        }
      }
    }
    __syncthreads();

    float alpha[4];
#pragma unroll
    for (int i = 0; i < 4; i++) {
      float rm;
#pragma unroll
      for (int j = 0; j < 4; j++) s[i][j] = s[i][j] * scale + mk[i][j];
      rm = fmaxf(fmaxf(s[i][0], s[i][1]), fmaxf(s[i][2], s[i][3]));
#pragma unroll
      for (int off = 1; off < 16; off <<= 1) rm = fmaxf(rm, __shfl_xor(rm, off));
      float mn = fmaxf(m_i[i], rm);
      alpha[i] = __expf(m_i[i] - mn);
      float rs = 0.f;
#pragma unroll
      for (int j = 0; j < 4; j++) { s[i][j] = __expf(s[i][j] - mn); rs += s[i][j]; }
#pragma unroll
      for (int off = 1; off < 16; off <<= 1) rs += __shfl_xor(rs, off);
      l_i[i] = l_i[i] * alpha[i] + rs;
      m_i[i] = mn;
#pragma unroll
      for (int c = 0; c < 8; c++) o[i][c] *= alpha[i];
    }
#pragma unroll
    for (int i = 0; i < 4; i++)
#pragma unroll
      for (int j = 0; j < 4; j++) Sg[(4 * ty + i) * 65 + 4 * tx + j] = s[i][j];
    __syncthreads();

#pragma unroll 2
    for (int kk = 0; kk < 64; kk++) {
      float p[4];
#pragma unroll
      for (int i = 0; i < 4; i++) p[i] = Sg[(4 * ty + i) * 65 + kk];
      unsigned v0 = VsU[kk * 65 + 2 * tx];
      unsigned v1 = VsU[kk * 65 + 2 * tx + 1];
      unsigned v2 = VsU[kk * 65 + 32 + 2 * tx];
      unsigned v3 = VsU[kk * 65 + 32 + 2 * tx + 1];
      float vv[8] = { bflo(v0), bfhi(v0), bflo(v1), bfhi(v1),
                      bflo(v2), bfhi(v2), bflo(v3), bfhi(v3) };
#pragma unroll
      for (int i = 0; i < 4; i++)
#pragma unroll
        for (int c = 0; c < 8; c++) o[i][c] += p[i] * vv[c];
    }
  }

#pragma unroll
  for (int i = 0; i < 4; i++) {
    float inv = 1.f / l_i[i];
    size_t base = (((size_t)(qblk + 4 * ty + i)) * H + hh) * D;
    ushort4 lo, hi;
    lo.x = f2bf(o[i][0] * inv); lo.y = f2bf(o[i][1] * inv);
    lo.z = f2bf(o[i][2] * inv); lo.w = f2bf(o[i][3] * inv);
    hi.x = f2bf(o[i][4] * inv); hi.y = f2bf(o[i][5] * inv);
    hi.z = f2bf(o[i][6] * inv); hi.w = f2bf(o[i][7] * inv);
    *(ushort4*)&ctx[base + 4 * tx] = lo;
    *(ushort4*)&ctx[base + 64 + 4 * tx] = hi;
  }
}

// ---------------------------------------------------------------------------
// silu(gate)*up, bf16 in/out, 8 elements per thread, gate updated in place.
// ---------------------------------------------------------------------------
__device__ __forceinline__ unsigned silu2(unsigned gw, unsigned uw) {
  float g0 = bflo(gw), g1 = bfhi(gw), u0 = bflo(uw), u1 = bfhi(uw);
  float r0 = g0 / (1.f + __expf(-g0)) * u0;
  float r1 = g1 / (1.f + __expf(-g1)) * u1;
  return ((unsigned)f2bf(r1) << 16) | f2bf(r0);
}
__global__ __launch_bounds__(256) void silu_mul_bf16_kernel(
    unsigned short* __restrict__ g, const unsigned short* __restrict__ u, int n8) {
  int i = blockIdx.x * 256 + threadIdx.x;
  if (i >= n8) return;
  uint4 G = *(const uint4*)&g[(size_t)i * 8];
  uint4 U = *(const uint4*)&u[(size_t)i * 8];
  G.x = silu2(G.x, U.x); G.y = silu2(G.y, U.y);
  G.z = silu2(G.z, U.z); G.w = silu2(G.w, U.w);
  *(uint4*)&g[(size_t)i * 8] = G;
}

// ---------------------------------------------------------------------------
extern "C" void kernel_launch(void* const* d_in, const int* in_sizes, int n_in,
                              void* d_out, int out_size, void* d_ws, size_t ws_size,
                              hipStream_t stream) {
  (void)in_sizes; (void)n_in; (void)out_size; (void)ws_size;
  const float* hidden_states = (const float*)d_in[0];
  const float* kv_hidden     = (const float*)d_in[1];
  const float* causal_mask   = (const float*)d_in[2];
  const float* w_q      = (const float*)d_in[3];
  const float* w_k      = (const float*)d_in[4];
  const float* w_v      = (const float*)d_in[5];
  const float* w_o      = (const float*)d_in[6];
  const float* q_norm_w = (const float*)d_in[7];
  const float* k_norm_w = (const float*)d_in[8];
  const float* ln1_w    = (const float*)d_in[9];
  const float* ln2_w    = (const float*)d_in[10];
  const float* w_gate   = (const float*)d_in[11];
  const float* w_up     = (const float*)d_in[12];
  const float* w_down   = (const float*)d_in[13];
  const int* positions    = (const int*)d_in[14];
  const int* kv_positions = (const int*)d_in[15];
  const int* hs_idxs      = (const int*)d_in[16];
  const int* key_idxs     = (const int*)d_in[17];

  // Workspace layout (bytes). Total ~147 MB (< previous 168 MB footprint).
  char* wsb = (char*)d_ws;
  float* maskg           = (float*)(wsb + 0);                  // 25165824 (SQ*SK*4)
  unsigned short* h_bf   = (unsigned short*)(wsb + 25165824);  //  8388608 (SQ*DM*2)
  unsigned short* hk_bf  = (unsigned short*)(wsb + 33554432);  // 12582912 (SK*DM*2)
  unsigned short* W1     = (unsigned short*)(wsb + 46137344);  // 25165824 (rotating wT)
  unsigned short* W2     = (unsigned short*)(wsb + 71303168);  // 25165824 (rotating wT)
  float* qb              = (float*)(wsb + 96468992);           // 16777216 (SQ*H*D*4)
  float* kb              = (float*)(wsb + 113246208);          // 12582912 (SK*HKV*D*4)
  float* vb              = (float*)(wsb + 125829120);          // 12582912
  unsigned short* ctx_bf = (unsigned short*)(wsb + 138412032); //  8388608 (SQ*H*D*2)
  // overlays (lifetime-disjoint, stream-ordered):
  unsigned short* gate_bf = (unsigned short*)wsb;              // over maskg (dead after attn)
  unsigned short* up_bf   = (unsigned short*)(wsb + 113246208);// over kb+vb (dead after attn)
  float* hidden           = qb;                                // over qb    (dead after attn)
  unsigned short* h2_bf   = h_bf;                              // over h_bf  (dead after q-proj)

  // 0) mask pre-gather + input layernorms (bf16 out)
  mask_gather_kernel<<<SQ, 256, 0, stream>>>(causal_mask, hs_idxs, key_idxs, maskg);
  rmsnorm_bf16_kernel<<<SQ, 256, 0, stream>>>(hidden_states, ln1_w, h_bf);
  rmsnorm_bf16_kernel<<<SK, 256, 0, stream>>>(kv_hidden, ln1_w, hk_bf);

  // 1) q/k/v projections (bf16 MFMA; weights transposed just-in-time)
  wt_bf16_kernel<<<dim3((H * D) / 64, DM / 64), 256, 0, stream>>>(w_q, W1, DM, H * D);
  wt_bf16_kernel<<<dim3((HKV * D) / 64, DM / 64), 256, 0, stream>>>(w_k, W2, DM, HKV * D);
  mgemm_kernel<false, false><<<dim3((H * D) / 128, SQ / 128), 256, 0, stream>>>(
      h_bf, W1, nullptr, qb, SQ, H * D, DM);
  mgemm_kernel<false, false><<<dim3((HKV * D) / 128, SK / 128), 256, 0, stream>>>(
      hk_bf, W2, nullptr, kb, SK, HKV * D, DM);
  wt_bf16_kernel<<<dim3((HKV * D) / 64, DM / 64), 256, 0, stream>>>(w_v, W1, DM, HKV * D);
  mgemm_kernel<false, false><<<dim3((HKV * D) / 128, SK / 128), 256, 0, stream>>>(
      hk_bf, W1, nullptr, vb, SK, HKV * D, DM);

  // 2) per-head q/k RMSNorm + RoPE (f32, in place)
  qknorm_rope_kernel<<<dim3(SQ, H), 128, 0, stream>>>(qb, q_norm_w, positions, H);
  qknorm_rope_kernel<<<dim3(SK, HKV), 128, 0, stream>>>(kb, k_norm_w, kv_positions, HKV);

  // 3) attention (flash, bf16 LDS, bf16 ctx out)
  attn_kernel<<<dim3(SQ / 64, H), 256, 0, stream>>>(qb, kb, vb, maskg, ctx_bf);

  // 4) o-proj + residual (fused Add)
  wt_bf16_kernel<<<dim3(DM / 64, (H * D) / 64), 256, 0, stream>>>(w_o, W2, H * D, DM);
  mgemm_kernel<true, false><<<dim3(DM / 128, SQ / 128), 256, 0, stream>>>(
      ctx_bf, W2, hidden_states, hidden, SQ, DM, H * D);

  // 5) post-attn norm + SwiGLU MLP
  rmsnorm_bf16_kernel<<<SQ, 256, 0, stream>>>(hidden, ln2_w, h2_bf);
  wt_bf16_kernel<<<dim3(FF / 64, DM / 64), 256, 0, stream>>>(w_gate, W1, DM, FF);
  wt_bf16_kernel<<<dim3(FF / 64, DM / 64), 256, 0, stream>>>(w_up, W2, DM, FF);
  mgemm_kernel<false, true><<<dim3(FF / 128, SQ / 128), 256, 0, stream>>>(
      h2_bf, W1, nullptr, gate_bf, SQ, FF, DM);
  mgemm_kernel<false, true><<<dim3(FF / 128, SQ / 128), 256, 0, stream>>>(
      h2_bf, W2, nullptr, up_bf, SQ, FF, DM);
  silu_mul_bf16_kernel<<<(SQ * FF / 8 + 255) / 256, 256, 0, stream>>>(
      gate_bf, up_bf, SQ * FF / 8);

  // 6) down-proj + final residual, straight to d_out (fused Add)
  wt_bf16_kernel<<<dim3(DM / 64, FF / 64), 256, 0, stream>>>(w_down, W1, FF, DM);
  mgemm_kernel<true, false><<<dim3(DM / 128, SQ / 128), 256, 0, stream>>>(
      gate_bf, W1, hidden, (float*)d_out, SQ, DM, FF);
}

// Round 2
// 892.100 us; speedup vs baseline: 5.9557x; 1.8350x over previous
//
#include <hip/hip_runtime.h>
#include <math.h>

// Problem constants (B=1 throughout)
constexpr int SQ = 2048, SK = 3072, TT = 4096, DM = 2048;
constexpr int H = 16, HKV = 8, D = 128, FF = 6144;
#define EPS 1e-6f

typedef __attribute__((ext_vector_type(8))) short short8;   // 8 bf16 = 4 VGPRs
typedef __attribute__((ext_vector_type(4))) float f32x4;    // MFMA accum

#define GLOBAL_AS __attribute__((address_space(1)))
#define LDS_AS __attribute__((address_space(3)))

__device__ __forceinline__ unsigned short f2bf(float f) {
  unsigned u = __float_as_uint(f);
  unsigned r = (u + 0x7fffu + ((u >> 16) & 1u)) >> 16;
  return (unsigned short)r;
}
__device__ __forceinline__ float bflo(unsigned w) { return __uint_as_float(w << 16); }
__device__ __forceinline__ float bfhi(unsigned w) { return __uint_as_float(w & 0xffff0000u); }

// ---------------------------------------------------------------------------
// Weight transpose + f32->bf16 cast: w[K][N] f32  ->  wT[N][K] bf16.
// ---------------------------------------------------------------------------
__global__ __launch_bounds__(256) void wt_bf16_kernel(
    const float* __restrict__ w, unsigned short* __restrict__ wT, int K, int N) {
  __shared__ unsigned short s[64][73];
  int n0 = blockIdx.x * 64, k0 = blockIdx.y * 64;
  int tid = threadIdx.x;
  int cn = (tid & 15) * 4, rk = tid >> 4;
#pragma unroll
  for (int p = 0; p < 4; p++) {
    int k = rk + p * 16;
    const float4 f = *(const float4*)&w[(size_t)(k0 + k) * N + n0 + cn];
    s[k][cn] = f2bf(f.x); s[k][cn + 1] = f2bf(f.y);
    s[k][cn + 2] = f2bf(f.z); s[k][cn + 3] = f2bf(f.w);
  }
  __syncthreads();
  int ck = (tid & 15) * 4, rn = tid >> 4;
#pragma unroll
  for (int p = 0; p < 4; p++) {
    int n = rn + p * 16;
    ushort4 o;
    o.x = s[ck][n]; o.y = s[ck + 1][n]; o.z = s[ck + 2][n]; o.w = s[ck + 3][n];
    *(ushort4*)&wT[(size_t)(n0 + n) * K + k0 + ck] = o;
  }
}

// ---------------------------------------------------------------------------
// V transpose + cast: vb f32 [SK][HKV*D] -> vt bf16 [HKV][D][SK] (kv-contig).
// grid (SK/64, D/64, HKV), block 256.
// ---------------------------------------------------------------------------
__global__ __launch_bounds__(256) void vtrans_kernel(
    const float* __restrict__ vb, unsigned short* __restrict__ vt) {
  __shared__ unsigned short s[64][72];
  int kv0 = blockIdx.x * 64, d0 = blockIdx.y * 64, kvh = blockIdx.z;
  int tid = threadIdx.x;
  int cd = (tid & 15) * 4, rk = tid >> 4;
#pragma unroll
  for (int p = 0; p < 4; p++) {
    int kv = rk + p * 16;
    const float4 f = *(const float4*)&vb[((size_t)(kv0 + kv) * HKV + kvh) * D + d0 + cd];
    s[kv][cd] = f2bf(f.x); s[kv][cd + 1] = f2bf(f.y);
    s[kv][cd + 2] = f2bf(f.z); s[kv][cd + 3] = f2bf(f.w);
  }
  __syncthreads();
  int ck = (tid & 15) * 4, rd = tid >> 4;
#pragma unroll
  for (int p = 0; p < 4; p++) {
    int d = rd + p * 16;
    ushort4 o;
    o.x = s[ck][d]; o.y = s[ck + 1][d]; o.z = s[ck + 2][d]; o.w = s[ck + 3][d];
    *(ushort4*)&vt[((size_t)kvh * D + d0 + d) * SK + kv0 + ck] = o;
  }
}

// ---------------------------------------------------------------------------
// RMSNorm over DM=2048 cols, f32 in -> bf16 out. block 256 (8 elems/thread).
// ---------------------------------------------------------------------------
__global__ __launch_bounds__(256) void rmsnorm_bf16_kernel(
    const float* __restrict__ x, const float* __restrict__ w,
    unsigned short* __restrict__ y) {
  int row = blockIdx.x;
  const float* xr = x + (size_t)row * DM;
  int c = threadIdx.x * 8;
  float4 a = *(const float4*)&xr[c];
  float4 b = *(const float4*)&xr[c + 4];
  float ss = a.x * a.x + a.y * a.y + a.z * a.z + a.w * a.w +
             b.x * b.x + b.y * b.y + b.z * b.z + b.w * b.w;
  for (int o = 32; o > 0; o >>= 1) ss += __shfl_down(ss, o);
  __shared__ float sred[4];
  int lane = threadIdx.x & 63, wid = threadIdx.x >> 6;
  if (lane == 0) sred[wid] = ss;
  __syncthreads();
  if (threadIdx.x == 0)
    sred[0] = rsqrtf((sred[0] + sred[1] + sred[2] + sred[3]) * (1.0f / (float)DM) + EPS);
  __syncthreads();
  float sc = sred[0];
  float4 wa = *(const float4*)&w[c];
  float4 wb = *(const float4*)&w[c + 4];
  ushort4 o1, o2;
  o1.x = f2bf(a.x * sc * wa.x); o1.y = f2bf(a.y * sc * wa.y);
  o1.z = f2bf(a.z * sc * wa.z); o1.w = f2bf(a.w * sc * wa.w);
  o2.x = f2bf(b.x * sc * wb.x); o2.y = f2bf(b.y * sc * wb.y);
  o2.z = f2bf(b.z * sc * wb.z); o2.w = f2bf(b.w * sc * wb.w);
  unsigned short* yr = y + (size_t)row * DM + c;
  *(ushort4*)&yr[0] = o1;
  *(ushort4*)&yr[4] = o2;
}

// ---------------------------------------------------------------------------
// bf16 MFMA GEMM (m97 structure): C[M,N] = A[M,K] @ BT[N,K]^T (+ Add)
// ---------------------------------------------------------------------------
template <bool ADD, bool OUTBF>
__global__ __launch_bounds__(256) void mgemm_kernel(
    const unsigned short* __restrict__ A, const unsigned short* __restrict__ BT,
    const float* __restrict__ Add, void* __restrict__ Cp,
    int M, int N, int K) {
  __shared__ unsigned short As[128 * 64];
  __shared__ unsigned short Bs[128 * 64];
  const int tid = threadIdx.x;
  const int wave = tid >> 6, lane = tid & 63;
  const int bm = blockIdx.y * 128, bn = blockIdx.x * 128;
  const int wr = wave >> 1, wc = wave & 1;
  const int fl = lane & 15, fk = lane >> 4;

  const int srow = wave * 8 + (lane >> 3);
  const int schunk = (lane & 7) ^ (srow & 7);
  const unsigned short* Abase = A + (size_t)(bm + srow) * K + schunk * 8;
  const unsigned short* Bbase = BT + (size_t)(bn + srow) * K + schunk * 8;

  f32x4 acc[4][4];
#pragma unroll
  for (int m = 0; m < 4; m++)
#pragma unroll
    for (int n = 0; n < 4; n++)
#pragma unroll
      for (int e = 0; e < 4; e++) acc[m][n][e] = 0.f;

  for (int k0 = 0; k0 < K; k0 += 64) {
#pragma unroll
    for (int p = 0; p < 4; p++) {
      __builtin_amdgcn_global_load_lds(
          (GLOBAL_AS unsigned*)(Abase + (size_t)(p * 32) * K + k0),
          (LDS_AS unsigned*)&As[(p * 32 + wave * 8) * 64], 16, 0, 0);
      __builtin_amdgcn_global_load_lds(
          (GLOBAL_AS unsigned*)(Bbase + (size_t)(p * 32) * K + k0),
          (LDS_AS unsigned*)&Bs[(p * 32 + wave * 8) * 64], 16, 0, 0);
    }
    __syncthreads();
#pragma unroll
    for (int kk = 0; kk < 2; kk++) {
      short8 a_[4], b_[4];
#pragma unroll
      for (int m = 0; m < 4; m++) {
        int row = wr * 64 + m * 16 + fl;
        int ch = (kk * 4 + fk) ^ (row & 7);
        a_[m] = *(const short8*)&As[row * 64 + ch * 8];
      }
#pragma unroll
      for (int n = 0; n < 4; n++) {
        int row = wc * 64 + n * 16 + fl;
        int ch = (kk * 4 + fk) ^ (row & 7);
        b_[n] = *(const short8*)&Bs[row * 64 + ch * 8];
      }
#pragma unroll
      for (int m = 0; m < 4; m++)
#pragma unroll
        for (int n = 0; n < 4; n++)
          acc[m][n] = __builtin_amdgcn_mfma_f32_16x16x32_bf16(
              a_[m], b_[n], acc[m][n], 0, 0, 0);
    }
    __syncthreads();
  }

#pragma unroll
  for (int m = 0; m < 4; m++) {
    int row0 = bm + wr * 64 + m * 16 + fk * 4;
#pragma unroll
    for (int n = 0; n < 4; n++) {
      int col = bn + wc * 64 + n * 16 + fl;
#pragma unroll
      for (int r = 0; r < 4; r++) {
        size_t idx = (size_t)(row0 + r) * N + col;
        float v = acc[m][n][r];
        if (ADD) v += Add[idx];
        if (OUTBF) ((unsigned short*)Cp)[idx] = f2bf(v);
        else ((float*)Cp)[idx] = v;
      }
    }
  }
}

// ---------------------------------------------------------------------------
// Per-head RMSNorm (over D=128) + RoPE; f32 in, bf16 HEAD-MAJOR out [h][S][D].
// ---------------------------------------------------------------------------
__global__ __launch_bounds__(128) void qknorm_rope_bf16_kernel(
    const float* __restrict__ x, const float* __restrict__ nw,
    const int* __restrict__ pos, unsigned short* __restrict__ out,
    int nheads, int S) {
  int s = blockIdx.x, hh = blockIdx.y;
  const float* xr = x + ((size_t)s * nheads + hh) * D;
  int d = threadIdx.x;
  float vv = xr[d];
  float ss = vv * vv;
  for (int o = 32; o > 0; o >>= 1) ss += __shfl_down(ss, o);
  __shared__ float sred[2];
  __shared__ float sn[D];
  if ((d & 63) == 0) sred[d >> 6] = ss;
  __syncthreads();
  float ms = (sred[0] + sred[1]) * (1.0f / (float)D);
  float n = vv * rsqrtf(ms + EPS) * nw[d];
  sn[d] = n;
  __syncthreads();
  int t = d & 63;
  float inv = powf(1000000.0f, -((float)(2 * t)) / (float)D);
  float ang = (float)pos[s] * inv;
  float c = cosf(ang), si = sinf(ang);
  float rh = (d < 64) ? -sn[d + 64] : sn[d - 64];
  out[((size_t)hh * S + s) * D + d] = f2bf(n * c + rh * si);
}

// ---------------------------------------------------------------------------
// Pre-gather mask: maskg[q][j] = mask[hs_idxs[q]*TT + key_idxs[j]]
// ---------------------------------------------------------------------------
__global__ __launch_bounds__(256) void mask_gather_kernel(
    const float* __restrict__ mask, const int* __restrict__ hs_idxs,
    const int* __restrict__ key_idxs, float* __restrict__ maskg) {
  int q = blockIdx.x;
  const float* base = mask + (size_t)hs_idxs[q] * TT;
  float* out = maskg + (size_t)q * SK;
  for (int j = threadIdx.x; j < SK; j += 256) out[j] = base[key_idxs[j]];
}

// ---------------------------------------------------------------------------
// MFMA flash attention. grid = 512 (XCD-swizzled -> (qblk, head)), block 256.
// qbf [H][SQ][D], kbf [HKV][SK][D], vtbf [HKV][D][SK] (bf16), maskg f32,
// ctx bf16 [SQ][H*D].
// Swapped QK^T: S^T = mfma(K, Q) -> lane holds S[q=fl][kv=16*kvf+4g+r].
// K/V tiles double-buffered (global_load_lds, XOR-swizzled source);
// one barrier per tile (stage t+1 issued before compute of t).
// ---------------------------------------------------------------------------
__global__ __launch_bounds__(256) void attn_mfma_kernel(
    const unsigned short* __restrict__ qbf, const unsigned short* __restrict__ kbf,
    const unsigned short* __restrict__ vtbf, const float* __restrict__ maskg,
    unsigned short* __restrict__ ctx) {
  __shared__ unsigned short Ks[2][64 * 128];
  __shared__ unsigned short Vts[2][128 * 64];
  __shared__ unsigned short Pl[4][16 * 72];   // per-wave P, row stride 72 (16B-aligned)

  const int tid = threadIdx.x;
  const int wave = tid >> 6, lane = tid & 63;
  const int fl = lane & 15, g = lane >> 4;
  const float scale = 0.08838834764831845f;  // 128^-0.5

  // XCD swizzle: 512 blocks, each XCD gets 64 contiguous work items = 2 heads.
  int bid = blockIdx.x;
  int swz = (bid & 7) * 64 + (bid >> 3);
  const int hh = swz >> 5;
  const int qblk = (swz & 31) * 64;
  const int kvh = hh >> 1;  // H/HKV == 2

  // Q fragments in registers (B-operand: rows [q][d])
  short8 qf[4];
  {
    const unsigned short* qrow = qbf + ((size_t)hh * SQ + qblk + wave * 16 + fl) * D;
#pragma unroll
    for (int kw = 0; kw < 4; kw++) qf[kw] = *(const short8*)&qrow[kw * 32 + g * 8];
  }

  // staging source pointers (pre-swizzled chunk; advance per tile)
  const unsigned short* ksrc[4];
  const unsigned short* vsrc[4];
  {
    int krow = lane >> 4;            // 0..3 (4 rows per K load)
    int vrow = lane >> 3;            // 0..7 (8 rows per V load)
    int vcs = (lane & 7) ^ vrow;
#pragma unroll
    for (int p = 0; p < 4; p++) {
      int rowk = wave * 16 + p * 4 + krow;
      int kcs = (lane & 15) ^ (rowk & 7);
      ksrc[p] = kbf + ((size_t)kvh * SK + rowk) * D + kcs * 8;
      int rowv = wave * 32 + p * 8 + vrow;
      vsrc[p] = vtbf + ((size_t)kvh * D + rowv) * SK + vcs * 8;
    }
  }
  const float* mbase = maskg + (size_t)(qblk + wave * 16 + fl) * SK + g * 4;

  float m_i = -INFINITY, l_i = 0.f;
  f32x4 o[8];
#pragma unroll
  for (int n = 0; n < 8; n++)
#pragma unroll
    for (int r = 0; r < 4; r++) o[n][r] = 0.f;

#define STAGE(bufi)                                                            \
  {                                                                            \
    _Pragma("unroll")                                                          \
    for (int p = 0; p < 4; p++) {                                              \
      __builtin_amdgcn_global_load_lds(                                        \
          (GLOBAL_AS unsigned*)ksrc[p],                                        \
          (LDS_AS unsigned*)&Ks[bufi][(wave * 16 + p * 4) * 128], 16, 0, 0);   \
      __builtin_amdgcn_global_load_lds(                                        \
          (GLOBAL_AS unsigned*)vsrc[p],                                        \
          (LDS_AS unsigned*)&Vts[bufi][(wave * 32 + p * 8) * 64], 16, 0, 0);   \
      ksrc[p] += 64 * D;                                                       \
      vsrc[p] += 64;                                                           \
    }                                                                          \
  }

  STAGE(0);
  __syncthreads();

  const int NT = SK / 64;
  for (int t = 0; t < NT; t++) {
    const int buf = t & 1;
    if (t + 1 < NT) STAGE(buf ^ 1);

    // mask prefetch (issues early, consumed after S)
    float4 mv[4];
#pragma unroll
    for (int kvf = 0; kvf < 4; kvf++) mv[kvf] = *(const float4*)(mbase + kvf * 16);
    mbase += 64;

    // ---- S^T = K · Q^T ----
    f32x4 sa[4];
#pragma unroll
    for (int kvf = 0; kvf < 4; kvf++)
#pragma unroll
      for (int r = 0; r < 4; r++) sa[kvf][r] = 0.f;
#pragma unroll
    for (int kw = 0; kw < 4; kw++) {
#pragma unroll
      for (int kvf = 0; kvf < 4; kvf++) {
        int row = kvf * 16 + fl;
        int ch = (kw * 4 + g) ^ (fl & 7);
        short8 kf = *(const short8*)&Ks[buf][row * 128 + ch * 8];
        sa[kvf] = __builtin_amdgcn_mfma_f32_16x16x32_bf16(kf, qf[kw], sa[kvf], 0, 0, 0);
      }
    }

    // ---- online softmax (lane: q = fl; kv values at 16*kvf + 4g + r) ----
    float p4[4][4];
    float rm = -INFINITY;
#pragma unroll
    for (int kvf = 0; kvf < 4; kvf++) {
      p4[kvf][0] = sa[kvf][0] * scale + mv[kvf].x;
      p4[kvf][1] = sa[kvf][1] * scale + mv[kvf].y;
      p4[kvf][2] = sa[kvf][2] * scale + mv[kvf].z;
      p4[kvf][3] = sa[kvf][3] * scale + mv[kvf].w;
#pragma unroll
      for (int r = 0; r < 4; r++) rm = fmaxf(rm, p4[kvf][r]);
    }
    rm = fmaxf(rm, __shfl_xor(rm, 16));
    rm = fmaxf(rm, __shfl_xor(rm, 32));
    float mn = fmaxf(m_i, rm);
    float alpha = __expf(m_i - mn);
    m_i = mn;
    float rs = 0.f;
#pragma unroll
    for (int kvf = 0; kvf < 4; kvf++) {
#pragma unroll
      for (int r = 0; r < 4; r++) { p4[kvf][r] = __expf(p4[kvf][r] - mn); rs += p4[kvf][r]; }
      ushort4 pk;
      pk.x = f2bf(p4[kvf][0]); pk.y = f2bf(p4[kvf][1]);
      pk.z = f2bf(p4[kvf][2]); pk.w = f2bf(p4[kvf][3]);
      *(ushort4*)&Pl[wave][fl * 72 + kvf * 16 + g * 4] = pk;
    }
    rs += __shfl_xor(rs, 16);
    rs += __shfl_xor(rs, 32);
    l_i = l_i * alpha + rs;

    // rescale O (O rows q = 4g + r; alpha held at lane fl = q)
    float av[4];
#pragma unroll
    for (int r = 0; r < 4; r++) av[r] = __shfl(alpha, 4 * g + r);
#pragma unroll
    for (int n = 0; n < 8; n++)
#pragma unroll
      for (int r = 0; r < 4; r++) o[n][r] *= av[r];

    // ---- O += P · V ----
#pragma unroll
    for (int k = 0; k < 2; k++) {
      short8 pf = *(const short8*)&Pl[wave][fl * 72 + k * 32 + g * 8];
#pragma unroll
      for (int n = 0; n < 8; n++) {
        int row = n * 16 + fl;
        int ch = (k * 4 + g) ^ (fl & 7);
        short8 vf = *(const short8*)&Vts[buf][row * 64 + ch * 8];
        o[n] = __builtin_amdgcn_mfma_f32_16x16x32_bf16(pf, vf, o[n], 0, 0, 0);
      }
    }
    __syncthreads();  // drains next-tile loads; all waves done with buf
  }

  // ---- epilogue: normalize, store bf16 ctx [SQ][H*D] ----
#pragma unroll
  for (int r = 0; r < 4; r++) {
    float linv = 1.f / __shfl(l_i, 4 * g + r);
    size_t base = ((size_t)(qblk + wave * 16 + 4 * g + r)) * (H * D) + (size_t)hh * D + fl;
#pragma unroll
    for (int n = 0; n < 8; n++) ctx[base + n * 16] = f2bf(o[n][r] * linv);
  }
#undef STAGE
}

// ---------------------------------------------------------------------------
// silu(gate)*up, bf16 in/out, 8 elements per thread, gate updated in place.
// ---------------------------------------------------------------------------
__device__ __forceinline__ unsigned silu2(unsigned gw, unsigned uw) {
  float g0 = bflo(gw), g1 = bfhi(gw), u0 = bflo(uw), u1 = bfhi(uw);
  float r0 = g0 / (1.f + __expf(-g0)) * u0;
  float r1 = g1 / (1.f + __expf(-g1)) * u1;
  return ((unsigned)f2bf(r1) << 16) | f2bf(r0);
}
__global__ __launch_bounds__(256) void silu_mul_bf16_kernel(
    unsigned short* __restrict__ g, const unsigned short* __restrict__ u, int n8) {
  int i = blockIdx.x * 256 + threadIdx.x;
  if (i >= n8) return;
  uint4 G = *(const uint4*)&g[(size_t)i * 8];
  uint4 U = *(const uint4*)&u[(size_t)i * 8];
  G.x = silu2(G.x, U.x); G.y = silu2(G.y, U.y);
  G.z = silu2(G.z, U.z); G.w = silu2(G.w, U.w);
  *(uint4*)&g[(size_t)i * 8] = G;
}

// ---------------------------------------------------------------------------
extern "C" void kernel_launch(void* const* d_in, const int* in_sizes, int n_in,
                              void* d_out, int out_size, void* d_ws, size_t ws_size,
                              hipStream_t stream) {
  (void)in_sizes; (void)n_in; (void)out_size; (void)ws_size;
  const float* hidden_states = (const float*)d_in[0];
  const float* kv_hidden     = (const float*)d_in[1];
  const float* causal_mask   = (const float*)d_in[2];
  const float* w_q      = (const float*)d_in[3];
  const float* w_k      = (const float*)d_in[4];
  const float* w_v      = (const float*)d_in[5];
  const float* w_o      = (const float*)d_in[6];
  const float* q_norm_w = (const float*)d_in[7];
  const float* k_norm_w = (const float*)d_in[8];
  const float* ln1_w    = (const float*)d_in[9];
  const float* ln2_w    = (const float*)d_in[10];
  const float* w_gate   = (const float*)d_in[11];
  const float* w_up     = (const float*)d_in[12];
  const float* w_down   = (const float*)d_in[13];
  const int* positions    = (const int*)d_in[14];
  const int* kv_positions = (const int*)d_in[15];
  const int* hs_idxs      = (const int*)d_in[16];
  const int* key_idxs     = (const int*)d_in[17];

  // Workspace layout (bytes), ~147 MB total.
  char* wsb = (char*)d_ws;
  float* maskg           = (float*)(wsb + 0);                  // 25165824
  unsigned short* h_bf   = (unsigned short*)(wsb + 25165824);  //  8388608
  unsigned short* hk_bf  = (unsigned short*)(wsb + 33554432);  // 12582912
  unsigned short* W1     = (unsigned short*)(wsb + 46137344);  // 25165824 (rotating wT)
  unsigned short* W2     = (unsigned short*)(wsb + 71303168);  // 25165824 (rotating wT)
  float* qb              = (float*)(wsb + 96468992);           // 16777216
  float* kb              = (float*)(wsb + 113246208);          // 12582912
  float* vb              = (float*)(wsb + 125829120);          // 12582912
  unsigned short* ctx_bf = (unsigned short*)(wsb + 138412032); //  8388608
  // overlays (lifetime-disjoint, stream-ordered):
  unsigned short* gate_bf = (unsigned short*)wsb;              // over maskg (dead after attn)
  unsigned short* up_bf   = (unsigned short*)(wsb + 113246208);// over kb+vb (dead after attn)
  float* hidden           = qb;                                // over qb    (dead after rope)
  unsigned short* h2_bf   = h_bf;                              // over h_bf  (dead after q-proj)
  // attention operands overlay W1's 25 MB slot (free between v-proj and gate wt):
  unsigned short* qbf    = (unsigned short*)(wsb + 46137344);  //  8388608 [H][SQ][D]
  unsigned short* kbf    = (unsigned short*)(wsb + 54525952);  //  6291456 [HKV][SK][D]
  unsigned short* vtbf   = (unsigned short*)(wsb + 60817408);  //  6291456 [HKV][D][SK]

  // 0) mask pre-gather + input layernorms (bf16 out)
  mask_gather_kernel<<<SQ, 256, 0, stream>>>(causal_mask, hs_idxs, key_idxs, maskg);
  rmsnorm_bf16_kernel<<<SQ, 256, 0, stream>>>(hidden_states, ln1_w, h_bf);
  rmsnorm_bf16_kernel<<<SK, 256, 0, stream>>>(kv_hidden, ln1_w, hk_bf);

  // 1) q/k/v projections (bf16 MFMA; weights transposed just-in-time)
  wt_bf16_kernel<<<dim3((H * D) / 64, DM / 64), 256, 0, stream>>>(w_q, W1, DM, H * D);
  wt_bf16_kernel<<<dim3((HKV * D) / 64, DM / 64), 256, 0, stream>>>(w_k, W2, DM, HKV * D);
  mgemm_kernel<false, false><<<dim3((H * D) / 128, SQ / 128), 256, 0, stream>>>(
      h_bf, W1, nullptr, qb, SQ, H * D, DM);
  mgemm_kernel<false, false><<<dim3((HKV * D) / 128, SK / 128), 256, 0, stream>>>(
      hk_bf, W2, nullptr, kb, SK, HKV * D, DM);
  wt_bf16_kernel<<<dim3((HKV * D) / 64, DM / 64), 256, 0, stream>>>(w_v, W1, DM, HKV * D);
  mgemm_kernel<false, false><<<dim3((HKV * D) / 128, SK / 128), 256, 0, stream>>>(
      hk_bf, W1, nullptr, vb, SK, HKV * D, DM);

  // 2) per-head q/k RMSNorm + RoPE -> bf16 head-major; V transpose -> [HKV][D][SK]
  qknorm_rope_bf16_kernel<<<dim3(SQ, H), 128, 0, stream>>>(
      qb, q_norm_w, positions, qbf, H, SQ);
  qknorm_rope_bf16_kernel<<<dim3(SK, HKV), 128, 0, stream>>>(
      kb, k_norm_w, kv_positions, kbf, HKV, SK);
  vtrans_kernel<<<dim3(SK / 64, D / 64, HKV), 256, 0, stream>>>(vb, vtbf);

  // 3) MFMA flash attention
  attn_mfma_kernel<<<512, 256, 0, stream>>>(qbf, kbf, vtbf, maskg, ctx_bf);

  // 4) o-proj + residual (fused Add)
  wt_bf16_kernel<<<dim3(DM / 64, (H * D) / 64), 256, 0, stream>>>(w_o, W2, H * D, DM);
  mgemm_kernel<true, false><<<dim3(DM / 128, SQ / 128), 256, 0, stream>>>(
      ctx_bf, W2, hidden_states, hidden, SQ, DM, H * D);

  // 5) post-attn norm + SwiGLU MLP
  rmsnorm_bf16_kernel<<<SQ, 256, 0, stream>>>(hidden, ln2_w, h2_bf);
  wt_bf16_kernel<<<dim3(FF / 64, DM / 64), 256, 0, stream>>>(w_gate, W1, DM, FF);
  wt_bf16_kernel<<<dim3(FF / 64, DM / 64), 256, 0, stream>>>(w_up, W2, DM, FF);
  mgemm_kernel<false, true><<<dim3(FF / 128, SQ / 128), 256, 0, stream>>>(
      h2_bf, W1, nullptr, gate_bf, SQ, FF, DM);
  mgemm_kernel<false, true><<<dim3(FF / 128, SQ / 128), 256, 0, stream>>>(
      h2_bf, W2, nullptr, up_bf, SQ, FF, DM);
  silu_mul_bf16_kernel<<<(SQ * FF / 8 + 255) / 256, 256, 0, stream>>>(
      gate_bf, up_bf, SQ * FF / 8);

  // 6) down-proj + final residual, straight to d_out (fused Add)
  wt_bf16_kernel<<<dim3(DM / 64, FF / 64), 256, 0, stream>>>(w_down, W1, FF, DM);
  mgemm_kernel<true, false><<<dim3(DM / 128, SQ / 128), 256, 0, stream>>>(
      gate_bf, W1, hidden, (float*)d_out, SQ, DM, FF);
}

// Round 3
// 873.727 us; speedup vs baseline: 6.0809x; 1.0210x over previous
//
#include <hip/hip_runtime.h>
#include <math.h>

// Problem constants (B=1 throughout)
constexpr int SQ = 2048, SK = 3072, TT = 4096, DM = 2048;
constexpr int H = 16, HKV = 8, D = 128, FF = 6144;
#define EPS 1e-6f

typedef __attribute__((ext_vector_type(8))) short short8;   // 8 bf16 = 4 VGPRs
typedef __attribute__((ext_vector_type(4))) float f32x4;    // MFMA accum

#define GLOBAL_AS __attribute__((address_space(1)))
#define LDS_AS __attribute__((address_space(3)))

__device__ __forceinline__ unsigned short f2bf(float f) {
  unsigned u = __float_as_uint(f);
  unsigned r = (u + 0x7fffu + ((u >> 16) & 1u)) >> 16;
  return (unsigned short)r;
}
__device__ __forceinline__ float bflo(unsigned w) { return __uint_as_float(w << 16); }
__device__ __forceinline__ float bfhi(unsigned w) { return __uint_as_float(w & 0xffff0000u); }

// ---------------------------------------------------------------------------
// Weight transpose + f32->bf16 cast: w[K][N] f32  ->  wT[N][K] bf16.
// ---------------------------------------------------------------------------
__global__ __launch_bounds__(256) void wt_bf16_kernel(
    const float* __restrict__ w, unsigned short* __restrict__ wT, int K, int N) {
  __shared__ unsigned short s[64][73];
  int n0 = blockIdx.x * 64, k0 = blockIdx.y * 64;
  int tid = threadIdx.x;
  int cn = (tid & 15) * 4, rk = tid >> 4;
#pragma unroll
  for (int p = 0; p < 4; p++) {
    int k = rk + p * 16;
    const float4 f = *(const float4*)&w[(size_t)(k0 + k) * N + n0 + cn];
    s[k][cn] = f2bf(f.x); s[k][cn + 1] = f2bf(f.y);
    s[k][cn + 2] = f2bf(f.z); s[k][cn + 3] = f2bf(f.w);
  }
  __syncthreads();
  int ck = (tid & 15) * 4, rn = tid >> 4;
#pragma unroll
  for (int p = 0; p < 4; p++) {
    int n = rn + p * 16;
    ushort4 o;
    o.x = s[ck][n]; o.y = s[ck + 1][n]; o.z = s[ck + 2][n]; o.w = s[ck + 3][n];
    *(ushort4*)&wT[(size_t)(n0 + n) * K + k0 + ck] = o;
  }
}

// ---------------------------------------------------------------------------
// V transpose + cast: vb f32 rows stride ldv -> vt bf16 [HKV][D][SK].
// grid (SK/64, D/64, HKV), block 256. vb points at the V column block.
// ---------------------------------------------------------------------------
__global__ __launch_bounds__(256) void vtrans_kernel(
    const float* __restrict__ vb, int ldv, unsigned short* __restrict__ vt) {
  __shared__ unsigned short s[64][72];
  int kv0 = blockIdx.x * 64, d0 = blockIdx.y * 64, kvh = blockIdx.z;
  int tid = threadIdx.x;
  int cd = (tid & 15) * 4, rk = tid >> 4;
#pragma unroll
  for (int p = 0; p < 4; p++) {
    int kv = rk + p * 16;
    const float4 f = *(const float4*)&vb[(size_t)(kv0 + kv) * ldv + kvh * D + d0 + cd];
    s[kv][cd] = f2bf(f.x); s[kv][cd + 1] = f2bf(f.y);
    s[kv][cd + 2] = f2bf(f.z); s[kv][cd + 3] = f2bf(f.w);
  }
  __syncthreads();
  int ck = (tid & 15) * 4, rd = tid >> 4;
#pragma unroll
  for (int p = 0; p < 4; p++) {
    int d = rd + p * 16;
    ushort4 o;
    o.x = s[ck][d]; o.y = s[ck + 1][d]; o.z = s[ck + 2][d]; o.w = s[ck + 3][d];
    *(ushort4*)&vt[((size_t)kvh * D + d0 + d) * SK + kv0 + ck] = o;
  }
}

// ---------------------------------------------------------------------------
// RMSNorm over DM=2048 cols, f32 in -> bf16 out. block 256 (8 elems/thread).
// ---------------------------------------------------------------------------
__global__ __launch_bounds__(256) void rmsnorm_bf16_kernel(
    const float* __restrict__ x, const float* __restrict__ w,
    unsigned short* __restrict__ y) {
  int row = blockIdx.x;
  const float* xr = x + (size_t)row * DM;
  int c = threadIdx.x * 8;
  float4 a = *(const float4*)&xr[c];
  float4 b = *(const float4*)&xr[c + 4];
  float ss = a.x * a.x + a.y * a.y + a.z * a.z + a.w * a.w +
             b.x * b.x + b.y * b.y + b.z * b.z + b.w * b.w;
  for (int o = 32; o > 0; o >>= 1) ss += __shfl_down(ss, o);
  __shared__ float sred[4];
  int lane = threadIdx.x & 63, wid = threadIdx.x >> 6;
  if (lane == 0) sred[wid] = ss;
  __syncthreads();
  if (threadIdx.x == 0)
    sred[0] = rsqrtf((sred[0] + sred[1] + sred[2] + sred[3]) * (1.0f / (float)DM) + EPS);
  __syncthreads();
  float sc = sred[0];
  float4 wa = *(const float4*)&w[c];
  float4 wb = *(const float4*)&w[c + 4];
  ushort4 o1, o2;
  o1.x = f2bf(a.x * sc * wa.x); o1.y = f2bf(a.y * sc * wa.y);
  o1.z = f2bf(a.z * sc * wa.z); o1.w = f2bf(a.w * sc * wa.w);
  o2.x = f2bf(b.x * sc * wb.x); o2.y = f2bf(b.y * sc * wb.y);
  o2.z = f2bf(b.z * sc * wb.z); o2.w = f2bf(b.w * sc * wb.w);
  unsigned short* yr = y + (size_t)row * DM + c;
  *(ushort4*)&yr[0] = o1;
  *(ushort4*)&yr[4] = o2;
}

// ---------------------------------------------------------------------------
// bf16 MFMA GEMM (m97 structure), dual-B/dual-C variant:
// C[M,N] = A[M,K] @ [BT1;BT2]^T, blocks with bn >= N1 use BT2/C2.
// 128x128 tile, BK=64, 4 waves x (64x64), mfma_f32_16x16x32_bf16.
// ---------------------------------------------------------------------------
template <bool OUTBF>
__global__ __launch_bounds__(256) void mgemm_kernel(
    const unsigned short* __restrict__ A, const unsigned short* __restrict__ BT1,
    const unsigned short* __restrict__ BT2, int N1,
    void* __restrict__ C1p, void* __restrict__ C2p, int ld1, int ld2,
    int M, int N, int K) {
  __shared__ unsigned short As[128 * 64];
  __shared__ unsigned short Bs[128 * 64];
  const int tid = threadIdx.x;
  const int wave = tid >> 6, lane = tid & 63;
  const int bm = blockIdx.y * 128, bn = blockIdx.x * 128;
  const bool second = bn >= N1;
  const unsigned short* BT = second ? BT2 : BT1;
  const int bnl = second ? bn - N1 : bn;
  void* Cp = second ? C2p : C1p;
  const int ldc = second ? ld2 : ld1;
  const int wr = wave >> 1, wc = wave & 1;
  const int fl = lane & 15, fk = lane >> 4;

  const int srow = wave * 8 + (lane >> 3);
  const int schunk = (lane & 7) ^ (srow & 7);
  const unsigned short* Abase = A + (size_t)(bm + srow) * K + schunk * 8;
  const unsigned short* Bbase = BT + (size_t)(bnl + srow) * K + schunk * 8;

  f32x4 acc[4][4];
#pragma unroll
  for (int m = 0; m < 4; m++)
#pragma unroll
    for (int n = 0; n < 4; n++)
#pragma unroll
      for (int e = 0; e < 4; e++) acc[m][n][e] = 0.f;

  for (int k0 = 0; k0 < K; k0 += 64) {
#pragma unroll
    for (int p = 0; p < 4; p++) {
      __builtin_amdgcn_global_load_lds(
          (GLOBAL_AS unsigned*)(Abase + (size_t)(p * 32) * K + k0),
          (LDS_AS unsigned*)&As[(p * 32 + wave * 8) * 64], 16, 0, 0);
      __builtin_amdgcn_global_load_lds(
          (GLOBAL_AS unsigned*)(Bbase + (size_t)(p * 32) * K + k0),
          (LDS_AS unsigned*)&Bs[(p * 32 + wave * 8) * 64], 16, 0, 0);
    }
    __syncthreads();
#pragma unroll
    for (int kk = 0; kk < 2; kk++) {
      short8 a_[4], b_[4];
#pragma unroll
      for (int m = 0; m < 4; m++) {
        int row = wr * 64 + m * 16 + fl;
        int ch = (kk * 4 + fk) ^ (row & 7);
        a_[m] = *(const short8*)&As[row * 64 + ch * 8];
      }
#pragma unroll
      for (int n = 0; n < 4; n++) {
        int row = wc * 64 + n * 16 + fl;
        int ch = (kk * 4 + fk) ^ (row & 7);
        b_[n] = *(const short8*)&Bs[row * 64 + ch * 8];
      }
#pragma unroll
      for (int m = 0; m < 4; m++)
#pragma unroll
        for (int n = 0; n < 4; n++)
          acc[m][n] = __builtin_amdgcn_mfma_f32_16x16x32_bf16(
              a_[m], b_[n], acc[m][n], 0, 0, 0);
    }
    __syncthreads();
  }

#pragma unroll
  for (int m = 0; m < 4; m++) {
    int row0 = bm + wr * 64 + m * 16 + fk * 4;
#pragma unroll
    for (int n = 0; n < 4; n++) {
      int col = bnl + wc * 64 + n * 16 + fl;
#pragma unroll
      for (int r = 0; r < 4; r++) {
        size_t idx = (size_t)(row0 + r) * ldc + col;
        float v = acc[m][n][r];
        if (OUTBF) ((unsigned short*)Cp)[idx] = f2bf(v);
        else ((float*)Cp)[idx] = v;
      }
    }
  }
}

// ---------------------------------------------------------------------------
// Split-K bf16 MFMA GEMM: C[M,N] += A[M,K_chunk] @ BT^T via f32 HW atomics.
// grid.z = num K chunks; C must be pre-initialized (zero or residual).
// ---------------------------------------------------------------------------
__global__ __launch_bounds__(256) void msplit_kernel(
    const unsigned short* __restrict__ A, const unsigned short* __restrict__ BT,
    float* __restrict__ C, int M, int N, int K, int kchunk) {
  __shared__ unsigned short As[128 * 64];
  __shared__ unsigned short Bs[128 * 64];
  const int tid = threadIdx.x;
  const int wave = tid >> 6, lane = tid & 63;
  const int bm = blockIdx.y * 128, bn = blockIdx.x * 128;
  const int kbeg = blockIdx.z * kchunk, kend = kbeg + kchunk;
  const int wr = wave >> 1, wc = wave & 1;
  const int fl = lane & 15, fk = lane >> 4;

  const int srow = wave * 8 + (lane >> 3);
  const int schunk = (lane & 7) ^ (srow & 7);
  const unsigned short* Abase = A + (size_t)(bm + srow) * K + schunk * 8;
  const unsigned short* Bbase = BT + (size_t)(bn + srow) * K + schunk * 8;

  f32x4 acc[4][4];
#pragma unroll
  for (int m = 0; m < 4; m++)
#pragma unroll
    for (int n = 0; n < 4; n++)
#pragma unroll
      for (int e = 0; e < 4; e++) acc[m][n][e] = 0.f;

  for (int k0 = kbeg; k0 < kend; k0 += 64) {
#pragma unroll
    for (int p = 0; p < 4; p++) {
      __builtin_amdgcn_global_load_lds(
          (GLOBAL_AS unsigned*)(Abase + (size_t)(p * 32) * K + k0),
          (LDS_AS unsigned*)&As[(p * 32 + wave * 8) * 64], 16, 0, 0);
      __builtin_amdgcn_global_load_lds(
          (GLOBAL_AS unsigned*)(Bbase + (size_t)(p * 32) * K + k0),
          (LDS_AS unsigned*)&Bs[(p * 32 + wave * 8) * 64], 16, 0, 0);
    }
    __syncthreads();
#pragma unroll
    for (int kk = 0; kk < 2; kk++) {
      short8 a_[4], b_[4];
#pragma unroll
      for (int m = 0; m < 4; m++) {
        int row = wr * 64 + m * 16 + fl;
        int ch = (kk * 4 + fk) ^ (row & 7);
        a_[m] = *(const short8*)&As[row * 64 + ch * 8];
      }
#pragma unroll
      for (int n = 0; n < 4; n++) {
        int row = wc * 64 + n * 16 + fl;
        int ch = (kk * 4 + fk) ^ (row & 7);
        b_[n] = *(const short8*)&Bs[row * 64 + ch * 8];
      }
#pragma unroll
      for (int m = 0; m < 4; m++)
#pragma unroll
        for (int n = 0; n < 4; n++)
          acc[m][n] = __builtin_amdgcn_mfma_f32_16x16x32_bf16(
              a_[m], b_[n], acc[m][n], 0, 0, 0);
    }
    __syncthreads();
  }

#pragma unroll
  for (int m = 0; m < 4; m++) {
    int row0 = bm + wr * 64 + m * 16 + fk * 4;
#pragma unroll
    for (int n = 0; n < 4; n++) {
      int col = bn + wc * 64 + n * 16 + fl;
#pragma unroll
      for (int r = 0; r < 4; r++)
        unsafeAtomicAdd(&C[(size_t)(row0 + r) * N + col], acc[m][n][r]);
    }
  }
}

// ---------------------------------------------------------------------------
// tiny init kernels (f32, float4-vectorized)
// ---------------------------------------------------------------------------
__global__ __launch_bounds__(256) void zero4_kernel(float4* __restrict__ p, int n4) {
  int i = blockIdx.x * 256 + threadIdx.x;
  if (i < n4) p[i] = make_float4(0.f, 0.f, 0.f, 0.f);
}
__global__ __launch_bounds__(256) void copy4_kernel(
    float4* __restrict__ d, const float4* __restrict__ s, int n4) {
  int i = blockIdx.x * 256 + threadIdx.x;
  if (i < n4) d[i] = s[i];
}

// ---------------------------------------------------------------------------
// Per-head RMSNorm (over D=128) + RoPE; f32 in (row stride ldx), bf16
// HEAD-MAJOR out [h][S][D].
// ---------------------------------------------------------------------------
__global__ __launch_bounds__(128) void qknorm_rope_bf16_kernel(
    const float* __restrict__ x, int ldx, const float* __restrict__ nw,
    const int* __restrict__ pos, unsigned short* __restrict__ out, int S) {
  int s = blockIdx.x, hh = blockIdx.y;
  const float* xr = x + (size_t)s * ldx + hh * D;
  int d = threadIdx.x;
  float vv = xr[d];
  float ss = vv * vv;
  for (int o = 32; o > 0; o >>= 1) ss += __shfl_down(ss, o);
  __shared__ float sred[2];
  __shared__ float sn[D];
  if ((d & 63) == 0) sred[d >> 6] = ss;
  __syncthreads();
  float ms = (sred[0] + sred[1]) * (1.0f / (float)D);
  float n = vv * rsqrtf(ms + EPS) * nw[d];
  sn[d] = n;
  __syncthreads();
  int t = d & 63;
  float inv = powf(1000000.0f, -((float)(2 * t)) / (float)D);
  float ang = (float)pos[s] * inv;
  float c = cosf(ang), si = sinf(ang);
  float rh = (d < 64) ? -sn[d + 64] : sn[d - 64];
  out[((size_t)hh * S + s) * D + d] = f2bf(n * c + rh * si);
}

// ---------------------------------------------------------------------------
// Pre-gather mask: maskg[q][j] = mask[hs_idxs[q]*TT + key_idxs[j]]
// ---------------------------------------------------------------------------
__global__ __launch_bounds__(256) void mask_gather_kernel(
    const float* __restrict__ mask, const int* __restrict__ hs_idxs,
    const int* __restrict__ key_idxs, float* __restrict__ maskg) {
  int q = blockIdx.x;
  const float* base = mask + (size_t)hs_idxs[q] * TT;
  float* out = maskg + (size_t)q * SK;
  for (int j = threadIdx.x; j < SK; j += 256) out[j] = base[key_idxs[j]];
}

// ---------------------------------------------------------------------------
// MFMA flash attention. grid = 512 (XCD-swizzled -> (qblk, head)), block 256.
// Swapped QK^T; K/V double-buffered via global_load_lds; defer-max (T13).
// ---------------------------------------------------------------------------
__global__ __launch_bounds__(256) void attn_mfma_kernel(
    const unsigned short* __restrict__ qbf, const unsigned short* __restrict__ kbf,
    const unsigned short* __restrict__ vtbf, const float* __restrict__ maskg,
    unsigned short* __restrict__ ctx) {
  __shared__ unsigned short Ks[2][64 * 128];
  __shared__ unsigned short Vts[2][128 * 64];
  __shared__ unsigned short Pl[4][16 * 72];

  const int tid = threadIdx.x;
  const int wave = tid >> 6, lane = tid & 63;
  const int fl = lane & 15, g = lane >> 4;
  const float scale = 0.08838834764831845f;  // 128^-0.5

  int bid = blockIdx.x;
  int swz = (bid & 7) * 64 + (bid >> 3);
  const int hh = swz >> 5;
  const int qblk = (swz & 31) * 64;
  const int kvh = hh >> 1;  // H/HKV == 2

  short8 qf[4];
  {
    const unsigned short* qrow = qbf + ((size_t)hh * SQ + qblk + wave * 16 + fl) * D;
#pragma unroll
    for (int kw = 0; kw < 4; kw++) qf[kw] = *(const short8*)&qrow[kw * 32 + g * 8];
  }

  const unsigned short* ksrc[4];
  const unsigned short* vsrc[4];
  {
    int krow = lane >> 4;
    int vrow = lane >> 3;
    int vcs = (lane & 7) ^ vrow;
#pragma unroll
    for (int p = 0; p < 4; p++) {
      int rowk = wave * 16 + p * 4 + krow;
      int kcs = (lane & 15) ^ (rowk & 7);
      ksrc[p] = kbf + ((size_t)kvh * SK + rowk) * D + kcs * 8;
      int rowv = wave * 32 + p * 8 + vrow;
      vsrc[p] = vtbf + ((size_t)kvh * D + rowv) * SK + vcs * 8;
    }
  }
  const float* mbase = maskg + (size_t)(qblk + wave * 16 + fl) * SK + g * 4;

  float m_i = -INFINITY, l_i = 0.f;
  f32x4 o[8];
#pragma unroll
  for (int n = 0; n < 8; n++)
#pragma unroll
    for (int r = 0; r < 4; r++) o[n][r] = 0.f;

#define STAGE(bufi)                                                            \
  {                                                                            \
    _Pragma("unroll")                                                          \
    for (int p = 0; p < 4; p++) {                                              \
      __builtin_amdgcn_global_load_lds(                                        \
          (GLOBAL_AS unsigned*)ksrc[p],                                        \
          (LDS_AS unsigned*)&Ks[bufi][(wave * 16 + p * 4) * 128], 16, 0, 0);   \
      __builtin_amdgcn_global_load_lds(                                        \
          (GLOBAL_AS unsigned*)vsrc[p],                                        \
          (LDS_AS unsigned*)&Vts[bufi][(wave * 32 + p * 8) * 64], 16, 0, 0);   \
      ksrc[p] += 64 * D;                                                       \
      vsrc[p] += 64;                                                           \
    }                                                                          \
  }

  STAGE(0);
  __syncthreads();

  const int NT = SK / 64;
  for (int t = 0; t < NT; t++) {
    const int buf = t & 1;
    if (t + 1 < NT) STAGE(buf ^ 1);

    float4 mv[4];
#pragma unroll
    for (int kvf = 0; kvf < 4; kvf++) mv[kvf] = *(const float4*)(mbase + kvf * 16);
    mbase += 64;

    // ---- S^T = K · Q^T ----
    f32x4 sa[4];
#pragma unroll
    for (int kvf = 0; kvf < 4; kvf++)
#pragma unroll
      for (int r = 0; r < 4; r++) sa[kvf][r] = 0.f;
#pragma unroll
    for (int kw = 0; kw < 4; kw++) {
#pragma unroll
      for (int kvf = 0; kvf < 4; kvf++) {
        int row = kvf * 16 + fl;
        int ch = (kw * 4 + g) ^ (fl & 7);
        short8 kf = *(const short8*)&Ks[buf][row * 128 + ch * 8];
        sa[kvf] = __builtin_amdgcn_mfma_f32_16x16x32_bf16(kf, qf[kw], sa[kvf], 0, 0, 0);
      }
    }

    // ---- online softmax with defer-max (T13, THR=8) ----
    float p4[4][4];
    float rm = -INFINITY;
#pragma unroll
    for (int kvf = 0; kvf < 4; kvf++) {
      p4[kvf][0] = sa[kvf][0] * scale + mv[kvf].x;
      p4[kvf][1] = sa[kvf][1] * scale + mv[kvf].y;
      p4[kvf][2] = sa[kvf][2] * scale + mv[kvf].z;
      p4[kvf][3] = sa[kvf][3] * scale + mv[kvf].w;
#pragma unroll
      for (int r = 0; r < 4; r++) rm = fmaxf(rm, p4[kvf][r]);
    }
    rm = fmaxf(rm, __shfl_xor(rm, 16));
    rm = fmaxf(rm, __shfl_xor(rm, 32));
    const int need = __any(rm > m_i + 8.f);
    float mn = need ? fmaxf(m_i, rm) : m_i;
    float alpha = need ? __expf(m_i - mn) : 1.f;
    m_i = mn;
    float rs = 0.f;
#pragma unroll
    for (int kvf = 0; kvf < 4; kvf++) {
#pragma unroll
      for (int r = 0; r < 4; r++) { p4[kvf][r] = __expf(p4[kvf][r] - mn); rs += p4[kvf][r]; }
      ushort4 pk;
      pk.x = f2bf(p4[kvf][0]); pk.y = f2bf(p4[kvf][1]);
      pk.z = f2bf(p4[kvf][2]); pk.w = f2bf(p4[kvf][3]);
      *(ushort4*)&Pl[wave][fl * 72 + kvf * 16 + g * 4] = pk;
    }
    rs += __shfl_xor(rs, 16);
    rs += __shfl_xor(rs, 32);
    l_i = l_i * alpha + rs;

    if (need) {
      float av[4];
#pragma unroll
      for (int r = 0; r < 4; r++) av[r] = __shfl(alpha, 4 * g + r);
#pragma unroll
      for (int n = 0; n < 8; n++)
#pragma unroll
        for (int r = 0; r < 4; r++) o[n][r] *= av[r];
    }

    // ---- O += P · V ----
#pragma unroll
    for (int k = 0; k < 2; k++) {
      short8 pf = *(const short8*)&Pl[wave][fl * 72 + k * 32 + g * 8];
#pragma unroll
      for (int n = 0; n < 8; n++) {
        int row = n * 16 + fl;
        int ch = (k * 4 + g) ^ (fl & 7);
        short8 vf = *(const short8*)&Vts[buf][row * 64 + ch * 8];
        o[n] = __builtin_amdgcn_mfma_f32_16x16x32_bf16(pf, vf, o[n], 0, 0, 0);
      }
    }
    __syncthreads();
  }

#pragma unroll
  for (int r = 0; r < 4; r++) {
    float linv = 1.f / __shfl(l_i, 4 * g + r);
    size_t base = ((size_t)(qblk + wave * 16 + 4 * g + r)) * (H * D) + (size_t)hh * D + fl;
#pragma unroll
    for (int n = 0; n < 8; n++) ctx[base + n * 16] = f2bf(o[n][r] * linv);
  }
#undef STAGE
}

// ---------------------------------------------------------------------------
// silu(gate)*up, bf16 in/out, 8 elements per thread, gate updated in place.
// ---------------------------------------------------------------------------
__device__ __forceinline__ unsigned silu2(unsigned gw, unsigned uw) {
  float g0 = bflo(gw), g1 = bfhi(gw), u0 = bflo(uw), u1 = bfhi(uw);
  float r0 = g0 / (1.f + __expf(-g0)) * u0;
  float r1 = g1 / (1.f + __expf(-g1)) * u1;
  return ((unsigned)f2bf(r1) << 16) | f2bf(r0);
}
__global__ __launch_bounds__(256) void silu_mul_bf16_kernel(
    unsigned short* __restrict__ g, const unsigned short* __restrict__ u, int n8) {
  int i = blockIdx.x * 256 + threadIdx.x;
  if (i >= n8) return;
  uint4 G = *(const uint4*)&g[(size_t)i * 8];
  uint4 U = *(const uint4*)&u[(size_t)i * 8];
  G.x = silu2(G.x, U.x); G.y = silu2(G.y, U.y);
  G.z = silu2(G.z, U.z); G.w = silu2(G.w, U.w);
  *(uint4*)&g[(size_t)i * 8] = G;
}

// ---------------------------------------------------------------------------
extern "C" void kernel_launch(void* const* d_in, const int* in_sizes, int n_in,
                              void* d_out, int out_size, void* d_ws, size_t ws_size,
                              hipStream_t stream) {
  (void)in_sizes; (void)n_in; (void)out_size; (void)ws_size;
  const float* hidden_states = (const float*)d_in[0];
  const float* kv_hidden     = (const float*)d_in[1];
  const float* causal_mask   = (const float*)d_in[2];
  const float* w_q      = (const float*)d_in[3];
  const float* w_k      = (const float*)d_in[4];
  const float* w_v      = (const float*)d_in[5];
  const float* w_o      = (const float*)d_in[6];
  const float* q_norm_w = (const float*)d_in[7];
  const float* k_norm_w = (const float*)d_in[8];
  const float* ln1_w    = (const float*)d_in[9];
  const float* ln2_w    = (const float*)d_in[10];
  const float* w_gate   = (const float*)d_in[11];
  const float* w_up     = (const float*)d_in[12];
  const float* w_down   = (const float*)d_in[13];
  const int* positions    = (const int*)d_in[14];
  const int* kv_positions = (const int*)d_in[15];
  const int* hs_idxs      = (const int*)d_in[16];
  const int* key_idxs     = (const int*)d_in[17];

  // Workspace layout (byte offsets), lifetime-overlaid; peak 134217728 B.
  char* wsb = (char*)d_ws;
  float* maskg           = (float*)(wsb + 0);                  // 25165824, T0->attn
  unsigned short* h_bf   = (unsigned short*)(wsb + 25165824);  //  8388608, ->qproj
  unsigned short* hk_bf  = (unsigned short*)(wsb + 33554432);  // 12582912, ->kvproj
  unsigned short* Wq     = (unsigned short*)(wsb + 46137344);  //  8388608, ->qproj
  unsigned short* Wkv    = (unsigned short*)(wsb + 54525952);  //  8388608, ->kvproj
  float* qb              = (float*)(wsb + 62914560);           // 16777216, ->rope_q
  float* kvb             = (float*)(wsb + 79691776);           // 25165824, ->vtrans
  unsigned short* qbf    = (unsigned short*)(wsb + 104857600); //  8388608, ->attn
  unsigned short* kbf    = (unsigned short*)(wsb + 113246208); //  6291456, ->attn
  unsigned short* vtbf   = (unsigned short*)(wsb + 119537664); //  6291456, ->attn
  unsigned short* ctx_bf = (unsigned short*)(wsb + 125829120); //  8388608, ->oproj
  // overlays (stream-ordered, lifetime-disjoint):
  float* hidden          = qb;                                 // over qb (dead after rope_q)
  unsigned short* Wo     = Wq;                                 // over Wq (dead after qproj)
  unsigned short* h2_bf  = h_bf;                               // over h_bf (dead after qproj)
  unsigned short* Wg     = (unsigned short*)(wsb + 0);         // over maskg (dead after attn)
  unsigned short* Wu     = (unsigned short*)(wsb + 79691776);  // over kvb (dead after vtrans)
  unsigned short* gate_bf = (unsigned short*)(wsb + 104857600);// over qbf..ctx (25165824)
  unsigned short* up_bf  = (unsigned short*)(wsb + 33554432);  // over hk/Wq/Wkv (25165824)
  unsigned short* Wd     = (unsigned short*)(wsb + 33554432);  // over up_bf (dead after silu)

  // 0) mask pre-gather + input layernorms (bf16 out)
  mask_gather_kernel<<<SQ, 256, 0, stream>>>(causal_mask, hs_idxs, key_idxs, maskg);
  rmsnorm_bf16_kernel<<<SQ, 256, 0, stream>>>(hidden_states, ln1_w, h_bf);
  rmsnorm_bf16_kernel<<<SK, 256, 0, stream>>>(kv_hidden, ln1_w, hk_bf);

  // 1) weight transposes for q / k|v (k,v stacked contiguously in Wkv)
  wt_bf16_kernel<<<dim3((H * D) / 64, DM / 64), 256, 0, stream>>>(w_q, Wq, DM, H * D);
  wt_bf16_kernel<<<dim3((HKV * D) / 64, DM / 64), 256, 0, stream>>>(w_k, Wkv, DM, HKV * D);
  wt_bf16_kernel<<<dim3((HKV * D) / 64, DM / 64), 256, 0, stream>>>(
      w_v, Wkv + (size_t)(HKV * D) * DM, DM, HKV * D);

  // 2) q-proj (split-K atomic, 512 blocks) + fused k|v-proj (384 blocks)
  zero4_kernel<<<(SQ * H * D / 4 + 255) / 256, 256, 0, stream>>>((float4*)qb, SQ * H * D / 4);
  msplit_kernel<<<dim3((H * D) / 128, SQ / 128, 2), 256, 0, stream>>>(
      h_bf, Wq, qb, SQ, H * D, DM, DM / 2);
  mgemm_kernel<false><<<dim3((2 * HKV * D) / 128, SK / 128), 256, 0, stream>>>(
      hk_bf, Wkv, nullptr, 2 * HKV * D, kvb, nullptr, 2 * HKV * D, 0, SK, 2 * HKV * D, DM);

  // 3) per-head q/k RMSNorm + RoPE -> bf16 head-major; V transpose
  qknorm_rope_bf16_kernel<<<dim3(SQ, H), 128, 0, stream>>>(
      qb, H * D, q_norm_w, positions, qbf, SQ);
  qknorm_rope_bf16_kernel<<<dim3(SK, HKV), 128, 0, stream>>>(
      kvb, 2 * HKV * D, k_norm_w, kv_positions, kbf, SK);
  vtrans_kernel<<<dim3(SK / 64, D / 64, HKV), 256, 0, stream>>>(
      kvb + HKV * D, 2 * HKV * D, vtbf);

  // 4) MFMA flash attention
  attn_mfma_kernel<<<512, 256, 0, stream>>>(qbf, kbf, vtbf, maskg, ctx_bf);

  // 5) o-proj + residual: hidden = hidden_states, then split-K atomic add
  copy4_kernel<<<(SQ * DM / 4 + 255) / 256, 256, 0, stream>>>(
      (float4*)hidden, (const float4*)hidden_states, SQ * DM / 4);
  wt_bf16_kernel<<<dim3(DM / 64, (H * D) / 64), 256, 0, stream>>>(w_o, Wo, H * D, DM);
  msplit_kernel<<<dim3(DM / 128, SQ / 128, 2), 256, 0, stream>>>(
      ctx_bf, Wo, hidden, SQ, DM, H * D, (H * D) / 2);

  // 6) post-attn norm + fused gate|up GEMM (1536 blocks) + silu
  rmsnorm_bf16_kernel<<<SQ, 256, 0, stream>>>(hidden, ln2_w, h2_bf);
  wt_bf16_kernel<<<dim3(FF / 64, DM / 64), 256, 0, stream>>>(w_gate, Wg, DM, FF);
  wt_bf16_kernel<<<dim3(FF / 64, DM / 64), 256, 0, stream>>>(w_up, Wu, DM, FF);
  mgemm_kernel<true><<<dim3((2 * FF) / 128, SQ / 128), 256, 0, stream>>>(
      h2_bf, Wg, Wu, FF, gate_bf, up_bf, FF, FF, SQ, 2 * FF, DM);
  silu_mul_bf16_kernel<<<(SQ * FF / 8 + 255) / 256, 256, 0, stream>>>(
      gate_bf, up_bf, SQ * FF / 8);

  // 7) down-proj + final residual: d_out = hidden, then split-K atomic add
  wt_bf16_kernel<<<dim3(DM / 64, FF / 64), 256, 0, stream>>>(w_down, Wd, FF, DM);
  copy4_kernel<<<(SQ * DM / 4 + 255) / 256, 256, 0, stream>>>(
      (float4*)d_out, (const float4*)hidden, SQ * DM / 4);
  msplit_kernel<<<dim3(DM / 128, SQ / 128, 3), 256, 0, stream>>>(
      gate_bf, Wd, (float*)d_out, SQ, DM, FF, FF / 3);
}